// Round 3
// baseline (695.960 us; speedup 1.0000x reference)
//
#include <hip/hip_runtime.h>
#include <hip/hip_bf16.h>

// DAGMM forward, fp32, round 3 (= round-2 design + ws_size-safe stats fallback).
//   K0 transpose_k : w1^T (60x120), w8^T (120x60) into d_ws
//   Kz zero_k      : zero the 150-float sums slot (needed for atomic fallback)
//   K1 mlp_k       : full AE + estimation net per row, fully register-resident
//                    (L1 fused into L2, L8 fused into L9, no LDS bounce),
//                    + fused GMM moment accumulation -> per-block partials
//                    (deterministic pp buffer if ws fits, else atomicAdd)
//   K2 reduce_k    : reduce 150 x nblk partials -> 150 sums   (pp mode only)
//   K3 consts_k    : mu/cov/Cholesky/log-consts; cov -> d_out
//   K4 energy_k    : per-row triangular solve + logsumexp -> energy
//
// d_out layout (floats): [energy N][gamma N*10][zc N*4][cov 160]
// d_ws  layout (floats): [w1t 7200][w8t 7200][pp 150*nblk][sums 152][consts 160]
//   (atomic mode: [w1t 7200][w8t 7200][sums 152][consts 160])

#define TPB 256

__device__ __forceinline__ float fast_tanh(float v) {
    // tanh(x) = 1 - 2/(exp(2x)+1); exp over/underflow give correct +-1 limits
    float e = __expf(2.0f * v);
    return 1.0f - __fdividef(2.0f, e + 1.0f);
}

__device__ __forceinline__ float wave_sum(float v) {
    #pragma unroll
    for (int off = 32; off > 0; off >>= 1) v += __shfl_xor(v, off, 64);
    return v;
}

// ---------------- K0: weight transposes ----------------
__global__ __launch_bounds__(256) void transpose_k(
    const float* __restrict__ w1, float* __restrict__ w1t,
    const float* __restrict__ w8, float* __restrict__ w8t) {
    int idx = blockIdx.x * 256 + threadIdx.x;
    if (idx < 7200) {
        int i1 = idx / 60,  j1 = idx % 60;    // w1: (120,60) -> w1t (60,120)
        w1t[j1 * 120 + i1] = w1[idx];
        int i8 = idx / 120, j8 = idx % 120;   // w8: (60,120) -> w8t (120,60)
        w8t[j8 * 60 + i8] = w8[idx];
    }
}

// ---------------- Kz: zero the sums slot ----------------
__global__ __launch_bounds__(256) void zero_k(float* __restrict__ sums) {
    if (threadIdx.x < 152) sums[threadIdx.x] = 0.0f;
}

// ---------------- K1: MLP + fused GMM moments ----------------
__global__ __launch_bounds__(TPB, 3) void mlp_k(
    const float* __restrict__ x,
    const float* __restrict__ w1t, const float* __restrict__ b1,
    const float* __restrict__ w2,  const float* __restrict__ b2,
    const float* __restrict__ w3,  const float* __restrict__ b3,
    const float* __restrict__ w4,  const float* __restrict__ b4,
    const float* __restrict__ w5,  const float* __restrict__ b5,
    const float* __restrict__ w6,  const float* __restrict__ b6,
    const float* __restrict__ w7,  const float* __restrict__ b7,
    const float* __restrict__ w8t, const float* __restrict__ b8,
    const float* __restrict__ w9,  const float* __restrict__ b9,
    const float* __restrict__ w10, const float* __restrict__ b10,
    float* __restrict__ g_out, float* __restrict__ z_out,
    float* __restrict__ pp, int nblk) {   // nblk==0 -> pp is sums, atomicAdd

    const int tid = threadIdx.x;
    const size_t row = (size_t)blockIdx.x * TPB + tid;

    // ---- load x row into registers, once (30 outstanding float4 loads) ----
    float4 xv[30];
    const float4* xr = (const float4*)(x + row * 120);
    #pragma unroll
    for (int i = 0; i < 30; ++i) xv[i] = xr[i];
    // pin: forbid rematerializing these loads inside the j-loop
    #pragma unroll
    for (int i = 0; i < 30; ++i)
        asm volatile("" : "+v"(xv[i].x), "+v"(xv[i].y), "+v"(xv[i].z), "+v"(xv[i].w));

    // ---- L1 (120->60, tanh) fused into L2 (60->30): h1 never materialized ----
    float h2[30];
    #pragma unroll
    for (int jj = 0; jj < 30; ++jj) h2[jj] = b2[jj];
    #pragma unroll 1
    for (int j = 0; j < 60; ++j) {
        const float* wr = w1t + j * 120;
        float a0 = 0.f, a1 = 0.f, a2 = 0.f, a3 = 0.f;
        float a4 = 0.f, a5 = 0.f, a6 = 0.f, a7 = 0.f;
        #pragma unroll
        for (int i0 = 0; i0 < 30; i0 += 2) {
            const float* wp = wr + i0 * 4;
            a0 = fmaf(xv[i0].x,     wp[0], a0);
            a1 = fmaf(xv[i0].y,     wp[1], a1);
            a2 = fmaf(xv[i0].z,     wp[2], a2);
            a3 = fmaf(xv[i0].w,     wp[3], a3);
            a4 = fmaf(xv[i0 + 1].x, wp[4], a4);
            a5 = fmaf(xv[i0 + 1].y, wp[5], a5);
            a6 = fmaf(xv[i0 + 1].z, wp[6], a6);
            a7 = fmaf(xv[i0 + 1].w, wp[7], a7);
        }
        float v = fast_tanh(((a0 + a4) + (a1 + a5)) + ((a2 + a6) + (a3 + a7)) + b1[j]);
        const float* w2r = w2 + j * 30;
        #pragma unroll
        for (int jj = 0; jj < 30; ++jj) h2[jj] = fmaf(v, w2r[jj], h2[jj]);
    }
    #pragma unroll
    for (int jj = 0; jj < 30; ++jj) h2[jj] = fast_tanh(h2[jj]);
    // xv dead from here on

    // ---- L3: 30 -> 10 (i-rolled, fully unrolled) ----
    float h3[10];
    #pragma unroll
    for (int j = 0; j < 10; ++j) h3[j] = b3[j];
    #pragma unroll
    for (int i = 0; i < 30; ++i) {
        const float* wr = w3 + i * 10;
        #pragma unroll
        for (int j = 0; j < 10; ++j) h3[j] = fmaf(h2[i], wr[j], h3[j]);
    }
    #pragma unroll
    for (int j = 0; j < 10; ++j) h3[j] = fast_tanh(h3[j]);

    // ---- L4: 10 -> 4 -> zc (latent, linear) ----
    float zc[4];
    #pragma unroll
    for (int j = 0; j < 4; ++j) zc[j] = b4[j];
    #pragma unroll
    for (int i = 0; i < 10; ++i) {
        #pragma unroll
        for (int j = 0; j < 4; ++j) zc[j] = fmaf(h3[i], w4[i * 4 + j], zc[j]);
    }

    // ---- L5: 4 -> 10 ----
    float h5[10];
    #pragma unroll
    for (int j = 0; j < 10; ++j) h5[j] = b5[j];
    #pragma unroll
    for (int i = 0; i < 4; ++i) {
        #pragma unroll
        for (int j = 0; j < 10; ++j) h5[j] = fmaf(zc[i], w5[i * 10 + j], h5[j]);
    }
    #pragma unroll
    for (int j = 0; j < 10; ++j) h5[j] = fast_tanh(h5[j]);

    // ---- L6: 10 -> 30 ----
    float h6[30];
    #pragma unroll
    for (int j = 0; j < 30; ++j) h6[j] = b6[j];
    #pragma unroll
    for (int i = 0; i < 10; ++i) {
        const float* wr = w6 + i * 30;
        #pragma unroll
        for (int j = 0; j < 30; ++j) h6[j] = fmaf(h5[i], wr[j], h6[j]);
    }
    #pragma unroll
    for (int j = 0; j < 30; ++j) h6[j] = fast_tanh(h6[j]);

    // ---- L7: 30 -> 60 (i-rolled, fully unrolled; h6 static-indexed) ----
    float h7[60];
    #pragma unroll
    for (int j = 0; j < 60; ++j) h7[j] = b7[j];
    #pragma unroll
    for (int i = 0; i < 30; ++i) {
        const float* wr = w7 + i * 60;
        #pragma unroll
        for (int j = 0; j < 60; ++j) h7[j] = fmaf(h6[i], wr[j], h7[j]);
    }
    #pragma unroll
    for (int j = 0; j < 60; ++j) h7[j] = fast_tanh(h7[j]);

    // ---- L8 (60->120, linear) fused into L9 (120->10): x_ never materialized ----
    float z9[10];
    #pragma unroll
    for (int c = 0; c < 10; ++c) z9[c] = b9[c];
    #pragma unroll 1
    for (int j = 0; j < 120; ++j) {
        const float* wr = w8t + j * 60;
        float a0 = b8[j], a1 = 0.f, a2 = 0.f, a3 = 0.f, a4 = 0.f, a5 = 0.f;
        #pragma unroll
        for (int i = 0; i < 60; i += 6) {
            a0 = fmaf(h7[i],     wr[i],     a0);
            a1 = fmaf(h7[i + 1], wr[i + 1], a1);
            a2 = fmaf(h7[i + 2], wr[i + 2], a2);
            a3 = fmaf(h7[i + 3], wr[i + 3], a3);
            a4 = fmaf(h7[i + 4], wr[i + 4], a4);
            a5 = fmaf(h7[i + 5], wr[i + 5], a5);
        }
        float xj = ((a0 + a1) + (a2 + a3)) + (a4 + a5);
        const float* w9r = w9 + j * 10;
        #pragma unroll
        for (int c = 0; c < 10; ++c) z9[c] = fmaf(xj, w9r[c], z9[c]);
    }
    #pragma unroll
    for (int c = 0; c < 10; ++c) z9[c] = fast_tanh(z9[c]);

    // ---- L10: 10 -> 10 + softmax ----
    float lg[10];
    #pragma unroll
    for (int j = 0; j < 10; ++j) lg[j] = b10[j];
    #pragma unroll
    for (int i = 0; i < 10; ++i) {
        const float* wr = w10 + i * 10;
        #pragma unroll
        for (int j = 0; j < 10; ++j) lg[j] = fmaf(z9[i], wr[j], lg[j]);
    }
    float mx = lg[0];
    #pragma unroll
    for (int k = 1; k < 10; ++k) mx = fmaxf(mx, lg[k]);
    float g[10];
    float s = 0.0f;
    #pragma unroll
    for (int k = 0; k < 10; ++k) { g[k] = __expf(lg[k] - mx); s += g[k]; }
    const float inv = __fdividef(1.0f, s);
    #pragma unroll
    for (int k = 0; k < 10; ++k) g[k] *= inv;

    // ---- stores (gamma: 8B-aligned float2; zc: float4) ----
    float2* gp = (float2*)(g_out + row * 10);
    #pragma unroll
    for (int k = 0; k < 5; ++k) gp[k] = make_float2(g[2 * k], g[2 * k + 1]);
    *(float4*)(z_out + row * 4) = make_float4(zc[0], zc[1], zc[2], zc[3]);

    // ---- fused GMM moment accumulation ----
    __shared__ float red[4][150];
    const int wave = tid >> 6, lane = tid & 63;
    const float z0 = zc[0], z1 = zc[1], z2 = zc[2], z3 = zc[3];
    #pragma unroll
    for (int k = 0; k < 10; ++k) {
        const float gv = g[k];
        const float t0 = gv * z0, t1 = gv * z1, t2 = gv * z2, t3 = gv * z3;
        float m[15];
        m[0] = gv;
        m[1] = t0;      m[2] = t1;      m[3] = t2;      m[4] = t3;
        m[5] = t0 * z0; m[6] = t0 * z1; m[7] = t0 * z2; m[8] = t0 * z3;
        m[9] = t1 * z1; m[10] = t1 * z2; m[11] = t1 * z3;
        m[12] = t2 * z2; m[13] = t2 * z3; m[14] = t3 * z3;
        #pragma unroll
        for (int i = 0; i < 15; ++i) {
            float sv = wave_sum(m[i]);
            if (lane == 0) red[wave][k * 15 + i] = sv;
        }
    }
    __syncthreads();
    if (tid < 150) {
        float sv = red[0][tid] + red[1][tid] + red[2][tid] + red[3][tid];
        if (nblk) pp[(size_t)tid * nblk + blockIdx.x] = sv;
        else      atomicAdd(pp + tid, sv);
    }
}

// ---------------- K2: reduce per-block partials (pp mode only) ----------------
__global__ __launch_bounds__(256) void reduce_k(
    const float* __restrict__ pp, float* __restrict__ sums, int nblk) {
    const int m = blockIdx.x;          // 0..149
    const float* p = pp + (size_t)m * nblk;
    float a = 0.0f;
    for (int t = threadIdx.x; t < nblk; t += 256) a += p[t];
    a = wave_sum(a);
    __shared__ float w[4];
    if ((threadIdx.x & 63) == 0) w[threadIdx.x >> 6] = a;
    __syncthreads();
    if (threadIdx.x == 0) sums[m] = (w[0] + w[1]) + (w[2] + w[3]);
}

// ---------------- K3: finalize GMM params ----------------
__global__ __launch_bounds__(256) void consts_k(
    const float* __restrict__ sums, float* __restrict__ consts,
    float* __restrict__ cov_out, int N) {
    __shared__ float sm[150];
    const int tid = threadIdx.x;
    if (tid < 150) sm[tid] = sums[tid];
    __syncthreads();
    if (tid < 10) {
        const int k = tid;
        const float sg = sm[k * 15 + 0];
        const float inv = 1.0f / sg;
        float mu[4];
        #pragma unroll
        for (int d = 0; d < 4; ++d) mu[d] = sm[k * 15 + 1 + d] * inv;
        const int pd[10] = {0,0,0,0,1,1,1,2,2,3};
        const int pe[10] = {0,1,2,3,1,2,3,2,3,3};
        float cov[4][4];
        #pragma unroll
        for (int p = 0; p < 10; ++p) {
            float cv = sm[k * 15 + 5 + p] * inv - mu[pd[p]] * mu[pe[p]];
            cov[pd[p]][pe[p]] = cv;
            cov[pe[p]][pd[p]] = cv;
        }
        #pragma unroll
        for (int d = 0; d < 4; ++d)
            #pragma unroll
            for (int e = 0; e < 4; ++e)
                cov_out[k * 16 + d * 4 + e] = cov[d][e];
        // jitter + Cholesky (4x4, lower)
        #pragma unroll
        for (int d = 0; d < 4; ++d) cov[d][d] += 1e-6f;
        float L00 = sqrtf(cov[0][0]);
        float L10 = cov[1][0] / L00, L20 = cov[2][0] / L00, L30 = cov[3][0] / L00;
        float L11 = sqrtf(cov[1][1] - L10 * L10);
        float L21 = (cov[2][1] - L20 * L10) / L11;
        float L31 = (cov[3][1] - L30 * L10) / L11;
        float L22 = sqrtf(cov[2][2] - L20 * L20 - L21 * L21);
        float L32 = (cov[3][2] - L30 * L20 - L31 * L21) / L22;
        float L33 = sqrtf(cov[3][3] - L30 * L30 - L31 * L31 - L32 * L32);
        float logdet = 2.0f * (logf(L00) + logf(L11) + logf(L22) + logf(L33));
        float phi = sg / (float)N;
        const float log2pi = 1.8378770664093453f;
        float ck = logf(phi) - 0.5f * (logdet + 4.0f * log2pi);
        float* cst = consts + k * 16;
        cst[0] = mu[0]; cst[1] = mu[1]; cst[2] = mu[2]; cst[3] = mu[3];
        cst[4] = L10; cst[5] = L20; cst[6] = L21;
        cst[7] = L30; cst[8] = L31; cst[9] = L32;
        cst[10] = 1.0f / L00; cst[11] = 1.0f / L11;
        cst[12] = 1.0f / L22; cst[13] = 1.0f / L33;
        cst[14] = ck;
    }
}

// ---------------- K4: sample energy ----------------
__global__ __launch_bounds__(256) void energy_k(
    const float* __restrict__ z_out, const float* __restrict__ consts,
    float* __restrict__ e_out) {
    __shared__ float cst[160];
    const int tid = threadIdx.x;
    if (tid < 160) cst[tid] = consts[tid];
    __syncthreads();
    const size_t row = (size_t)blockIdx.x * 256 + tid;
    float4 z = *(const float4*)(z_out + row * 4);
    float lp[10];
    float mx = -1e30f;
    #pragma unroll
    for (int k = 0; k < 10; ++k) {
        const float* q = cst + k * 16;
        float v0 = z.x - q[0], v1 = z.y - q[1], v2 = z.z - q[2], v3 = z.w - q[3];
        float y0 = v0 * q[10];
        float y1 = (v1 - q[4] * y0) * q[11];
        float y2 = (v2 - q[5] * y0 - q[6] * y1) * q[12];
        float y3 = (v3 - q[7] * y0 - q[8] * y1 - q[9] * y2) * q[13];
        float m = y0 * y0 + y1 * y1 + y2 * y2 + y3 * y3;
        lp[k] = q[14] - 0.5f * m;
        mx = fmaxf(mx, lp[k]);
    }
    float s = 0.0f;
    #pragma unroll
    for (int k = 0; k < 10; ++k) s += __expf(lp[k] - mx);
    e_out[row] = -(mx + __logf(s));
}

extern "C" void kernel_launch(void* const* d_in, const int* in_sizes, int n_in,
                              void* d_out, int out_size, void* d_ws, size_t ws_size,
                              hipStream_t stream) {
    const float* x = (const float*)d_in[0];
    const float* W[10];
    const float* B[10];
    for (int i = 0; i < 10; ++i) {
        W[i] = (const float*)d_in[1 + 2 * i];
        B[i] = (const float*)d_in[2 + 2 * i];
    }
    const int N = in_sizes[0] / 120;
    const int nblk = N / TPB;

    float* out   = (float*)d_out;
    float* e_out = out;                  // [N]
    float* g_out = out + (size_t)N;      // [N,10]
    float* z_out = out + (size_t)11 * N; // [N,4]
    float* c_out = out + (size_t)15 * N; // [10,4,4]

    float* ws  = (float*)d_ws;
    float* w1t = ws;                     // 7200
    float* w8t = ws + 7200;              // 7200

    // Deterministic per-block partials need 150*nblk floats; fall back to
    // atomics when the workspace can't hold them.
    const size_t need_pp = (size_t)(14400 + 150 * nblk + 152 + 160) * sizeof(float);
    const bool   fit     = ws_size >= need_pp;

    float* pp   = ws + 14400;                              // pp-mode partials
    float* sums = fit ? pp + (size_t)150 * nblk : ws + 14400;
    float* cst  = sums + 152;

    transpose_k<<<29, 256, 0, stream>>>(W[0], w1t, W[7], w8t);
    zero_k<<<1, 256, 0, stream>>>(sums);   // harmless in pp mode

    mlp_k<<<nblk, TPB, 0, stream>>>(
        x,
        w1t,  B[0],
        W[1], B[1],
        W[2], B[2],
        W[3], B[3],
        W[4], B[4],
        W[5], B[5],
        W[6], B[6],
        w8t,  B[7],
        W[8], B[8],
        W[9], B[9],
        g_out, z_out,
        fit ? pp : sums, fit ? nblk : 0);

    if (fit) reduce_k<<<150, 256, 0, stream>>>(pp, sums, nblk);
    consts_k<<<1, 256, 0, stream>>>(sums, cst, c_out, N);
    energy_k<<<N / 256, 256, 0, stream>>>(z_out, cst, e_out);
}

// Round 5
// 531.196 us; speedup vs baseline: 1.3102x; 1.3102x over previous
//
#include <hip/hip_runtime.h>
#include <hip/hip_bf16.h>

// DAGMM forward, fp32, round 5 (= round-4 design, resubmitted after
// GPU-acquisition timeout; never measured).
//   K0 prep_k   : w8^T (120x60) into d_ws + zero the 152-float sums slot
//   K1 mlp_k    : LDS-staged x (24-col chunks, coalesced), L1 i-rolled from LDS,
//                 L2..L7 register-resident, L8 fused into L9; fused GMM moments
//                 accumulated via atomicAdd into sums (tolerance headroom proven)
//   K2 energy_k : consts/Cholesky computed redundantly per block (tiny), then
//                 per-row triangular solve + logsumexp; block 0 writes cov
//
// d_out layout (floats): [energy N][gamma N*10][zc N*4][cov 160]
// d_ws  layout (floats): [w8t 7200][sums 152]

#define TPB 256

__device__ __forceinline__ float fast_tanh(float v) {
    // tanh(x) = 1 - 2/(exp(2x)+1); exp over/underflow give correct +-1 limits
    float e = __expf(2.0f * v);
    return 1.0f - __fdividef(2.0f, e + 1.0f);
}

__device__ __forceinline__ float wave_sum(float v) {
    #pragma unroll
    for (int off = 32; off > 0; off >>= 1) v += __shfl_xor(v, off, 64);
    return v;
}

// ---------------- K0: w8 transpose + zero sums ----------------
__global__ __launch_bounds__(256) void prep_k(
    const float* __restrict__ w8, float* __restrict__ w8t,
    float* __restrict__ sums) {
    int idx = blockIdx.x * 256 + threadIdx.x;
    if (idx < 7200) {
        int i8 = idx / 120, j8 = idx % 120;   // w8: (60,120) -> w8t (120,60)
        w8t[j8 * 60 + i8] = w8[idx];
    }
    if (idx < 152) sums[idx] = 0.0f;
}

// ---------------- K1: MLP + fused GMM moments ----------------
__global__ __launch_bounds__(TPB, 4) void mlp_k(
    const float* __restrict__ x,
    const float* __restrict__ w1,  const float* __restrict__ b1,
    const float* __restrict__ w2,  const float* __restrict__ b2,
    const float* __restrict__ w3,  const float* __restrict__ b3,
    const float* __restrict__ w4,  const float* __restrict__ b4,
    const float* __restrict__ w5,  const float* __restrict__ b5,
    const float* __restrict__ w6,  const float* __restrict__ b6,
    const float* __restrict__ w7,  const float* __restrict__ b7,
    const float* __restrict__ w8t, const float* __restrict__ b8,
    const float* __restrict__ w9,  const float* __restrict__ b9,
    const float* __restrict__ w10, const float* __restrict__ b10,
    float* __restrict__ g_out, float* __restrict__ z_out,
    float* __restrict__ sums) {

    __shared__ float smem[TPB * 25];      // x chunk buffer [256 rows][pitch 25]
    const int tid = threadIdx.x;
    const int row0 = blockIdx.x * TPB;
    const size_t row = (size_t)row0 + tid;

    // ---- L1: 120 -> 60, i-rolled; x staged to LDS in 24-col chunks ----
    // If the allocator splits the h1[60] accumulator pass, re-reads hit LDS
    // (cheap), not HBM — unlike rounds 1/3.
    float h1[60];
    #pragma unroll
    for (int j = 0; j < 60; ++j) h1[j] = b1[j];

    #pragma unroll 1
    for (int c0 = 0; c0 < 120; c0 += 24) {
        __syncthreads();
        // coalesced stage: 256 rows x 6 float4 = 1536 float4, 6 per thread
        #pragma unroll
        for (int it = 0; it < 6; ++it) {
            int idx = it * TPB + tid;
            int r = idx / 6, cl = idx - r * 6;
            float4 v = *(const float4*)(x + (size_t)(row0 + r) * 120 + c0 + cl * 4);
            float* dst = &smem[r * 25 + cl * 4];
            dst[0] = v.x; dst[1] = v.y; dst[2] = v.z; dst[3] = v.w;
        }
        __syncthreads();
        const float* wrow = w1 + c0 * 60;
        #pragma unroll 4
        for (int i = 0; i < 24; ++i) {
            float v = smem[tid * 25 + i];       // stride 25: conflict-free
            const float* wr = wrow + i * 60;    // wave-uniform -> s_load
            #pragma unroll
            for (int j = 0; j < 60; ++j) h1[j] = fmaf(v, wr[j], h1[j]);
        }
    }
    #pragma unroll
    for (int j = 0; j < 60; ++j) h1[j] = fast_tanh(h1[j]);

    // ---- L2: 60 -> 30 (fully unrolled, register-resident) ----
    float h2[30];
    #pragma unroll
    for (int j = 0; j < 30; ++j) h2[j] = b2[j];
    #pragma unroll
    for (int i = 0; i < 60; ++i) {
        const float* wr = w2 + i * 30;
        #pragma unroll
        for (int j = 0; j < 30; ++j) h2[j] = fmaf(h1[i], wr[j], h2[j]);
    }
    #pragma unroll
    for (int j = 0; j < 30; ++j) h2[j] = fast_tanh(h2[j]);

    // ---- L3: 30 -> 10 ----
    float h3[10];
    #pragma unroll
    for (int j = 0; j < 10; ++j) h3[j] = b3[j];
    #pragma unroll
    for (int i = 0; i < 30; ++i) {
        const float* wr = w3 + i * 10;
        #pragma unroll
        for (int j = 0; j < 10; ++j) h3[j] = fmaf(h2[i], wr[j], h3[j]);
    }
    #pragma unroll
    for (int j = 0; j < 10; ++j) h3[j] = fast_tanh(h3[j]);

    // ---- L4: 10 -> 4 -> zc (latent, linear) ----
    float zc[4];
    #pragma unroll
    for (int j = 0; j < 4; ++j) zc[j] = b4[j];
    #pragma unroll
    for (int i = 0; i < 10; ++i) {
        #pragma unroll
        for (int j = 0; j < 4; ++j) zc[j] = fmaf(h3[i], w4[i * 4 + j], zc[j]);
    }

    // ---- L5: 4 -> 10 ----
    float h5[10];
    #pragma unroll
    for (int j = 0; j < 10; ++j) h5[j] = b5[j];
    #pragma unroll
    for (int i = 0; i < 4; ++i) {
        #pragma unroll
        for (int j = 0; j < 10; ++j) h5[j] = fmaf(zc[i], w5[i * 10 + j], h5[j]);
    }
    #pragma unroll
    for (int j = 0; j < 10; ++j) h5[j] = fast_tanh(h5[j]);

    // ---- L6: 10 -> 30 ----
    float h6[30];
    #pragma unroll
    for (int j = 0; j < 30; ++j) h6[j] = b6[j];
    #pragma unroll
    for (int i = 0; i < 10; ++i) {
        const float* wr = w6 + i * 30;
        #pragma unroll
        for (int j = 0; j < 30; ++j) h6[j] = fmaf(h5[i], wr[j], h6[j]);
    }
    #pragma unroll
    for (int j = 0; j < 30; ++j) h6[j] = fast_tanh(h6[j]);

    // ---- L7: 30 -> 60 (fully unrolled) ----
    float h7[60];
    #pragma unroll
    for (int j = 0; j < 60; ++j) h7[j] = b7[j];
    #pragma unroll
    for (int i = 0; i < 30; ++i) {
        const float* wr = w7 + i * 60;
        #pragma unroll
        for (int j = 0; j < 60; ++j) h7[j] = fmaf(h6[i], wr[j], h7[j]);
    }
    #pragma unroll
    for (int j = 0; j < 60; ++j) h7[j] = fast_tanh(h7[j]);

    // ---- L8 (60->120, linear) fused into L9 (120->10): x_ never materialized ----
    float z9[10];
    #pragma unroll
    for (int c = 0; c < 10; ++c) z9[c] = b9[c];
    #pragma unroll 1
    for (int j = 0; j < 120; ++j) {
        const float* wr = w8t + j * 60;         // wave-uniform -> s_load
        float a0 = b8[j], a1 = 0.f, a2 = 0.f, a3 = 0.f, a4 = 0.f, a5 = 0.f;
        #pragma unroll
        for (int i = 0; i < 60; i += 6) {
            a0 = fmaf(h7[i],     wr[i],     a0);
            a1 = fmaf(h7[i + 1], wr[i + 1], a1);
            a2 = fmaf(h7[i + 2], wr[i + 2], a2);
            a3 = fmaf(h7[i + 3], wr[i + 3], a3);
            a4 = fmaf(h7[i + 4], wr[i + 4], a4);
            a5 = fmaf(h7[i + 5], wr[i + 5], a5);
        }
        float xj = ((a0 + a1) + (a2 + a3)) + (a4 + a5);
        const float* w9r = w9 + j * 10;
        #pragma unroll
        for (int c = 0; c < 10; ++c) z9[c] = fmaf(xj, w9r[c], z9[c]);
    }
    #pragma unroll
    for (int c = 0; c < 10; ++c) z9[c] = fast_tanh(z9[c]);

    // ---- L10: 10 -> 10 + softmax ----
    float lg[10];
    #pragma unroll
    for (int j = 0; j < 10; ++j) lg[j] = b10[j];
    #pragma unroll
    for (int i = 0; i < 10; ++i) {
        const float* wr = w10 + i * 10;
        #pragma unroll
        for (int j = 0; j < 10; ++j) lg[j] = fmaf(z9[i], wr[j], lg[j]);
    }
    float mx = lg[0];
    #pragma unroll
    for (int k = 1; k < 10; ++k) mx = fmaxf(mx, lg[k]);
    float g[10];
    float s = 0.0f;
    #pragma unroll
    for (int k = 0; k < 10; ++k) { g[k] = __expf(lg[k] - mx); s += g[k]; }
    const float inv = __fdividef(1.0f, s);
    #pragma unroll
    for (int k = 0; k < 10; ++k) g[k] *= inv;

    // ---- stores (gamma: float2 x5; zc: float4) ----
    float2* gp = (float2*)(g_out + row * 10);
    #pragma unroll
    for (int k = 0; k < 5; ++k) gp[k] = make_float2(g[2 * k], g[2 * k + 1]);
    *(float4*)(z_out + row * 4) = make_float4(zc[0], zc[1], zc[2], zc[3]);

    // ---- fused GMM moment accumulation (reuse smem; x buffer is dead) ----
    __syncthreads();
    float* red = smem;                    // [4][150]
    const int wave = tid >> 6, lane = tid & 63;
    const float z0 = zc[0], z1 = zc[1], z2 = zc[2], z3 = zc[3];
    #pragma unroll
    for (int k = 0; k < 10; ++k) {
        const float gv = g[k];
        const float t0 = gv * z0, t1 = gv * z1, t2 = gv * z2, t3 = gv * z3;
        float m[15];
        m[0] = gv;
        m[1] = t0;      m[2] = t1;      m[3] = t2;      m[4] = t3;
        m[5] = t0 * z0; m[6] = t0 * z1; m[7] = t0 * z2; m[8] = t0 * z3;
        m[9] = t1 * z1; m[10] = t1 * z2; m[11] = t1 * z3;
        m[12] = t2 * z2; m[13] = t2 * z3; m[14] = t3 * z3;
        #pragma unroll
        for (int i = 0; i < 15; ++i) {
            float sv = wave_sum(m[i]);
            if (lane == 0) red[wave * 150 + k * 15 + i] = sv;
        }
    }
    __syncthreads();
    if (tid < 150) {
        float sv = (red[tid] + red[150 + tid]) + (red[300 + tid] + red[450 + tid]);
        atomicAdd(sums + tid, sv);
    }
}

// ---------------- K2: consts (redundant per block) + sample energy ----------------
__global__ __launch_bounds__(256) void energy_k(
    const float* __restrict__ z_out, const float* __restrict__ sums,
    float* __restrict__ e_out, float* __restrict__ cov_out, int N) {
    __shared__ float sm[150];
    __shared__ float cst[160];
    const int tid = threadIdx.x;
    if (tid < 150) sm[tid] = sums[tid];
    __syncthreads();
    if (tid < 10) {
        const int k = tid;
        const float sg = sm[k * 15 + 0];
        const float inv = 1.0f / sg;
        float mu[4];
        #pragma unroll
        for (int d = 0; d < 4; ++d) mu[d] = sm[k * 15 + 1 + d] * inv;
        const int pd[10] = {0,0,0,0,1,1,1,2,2,3};
        const int pe[10] = {0,1,2,3,1,2,3,2,3,3};
        float cov[4][4];
        #pragma unroll
        for (int p = 0; p < 10; ++p) {
            float cv = sm[k * 15 + 5 + p] * inv - mu[pd[p]] * mu[pe[p]];
            cov[pd[p]][pe[p]] = cv;
            cov[pe[p]][pd[p]] = cv;
        }
        if (blockIdx.x == 0) {
            #pragma unroll
            for (int d = 0; d < 4; ++d)
                #pragma unroll
                for (int e = 0; e < 4; ++e)
                    cov_out[k * 16 + d * 4 + e] = cov[d][e];
        }
        // jitter + Cholesky (4x4, lower)
        #pragma unroll
        for (int d = 0; d < 4; ++d) cov[d][d] += 1e-6f;
        float L00 = sqrtf(cov[0][0]);
        float L10 = cov[1][0] / L00, L20 = cov[2][0] / L00, L30 = cov[3][0] / L00;
        float L11 = sqrtf(cov[1][1] - L10 * L10);
        float L21 = (cov[2][1] - L20 * L10) / L11;
        float L31 = (cov[3][1] - L30 * L10) / L11;
        float L22 = sqrtf(cov[2][2] - L20 * L20 - L21 * L21);
        float L32 = (cov[3][2] - L30 * L20 - L31 * L21) / L22;
        float L33 = sqrtf(cov[3][3] - L30 * L30 - L31 * L31 - L32 * L32);
        float logdet = 2.0f * (logf(L00) + logf(L11) + logf(L22) + logf(L33));
        float phi = sg / (float)N;
        const float log2pi = 1.8378770664093453f;
        float ck = logf(phi) - 0.5f * (logdet + 4.0f * log2pi);
        float* c = cst + k * 16;
        c[0] = mu[0]; c[1] = mu[1]; c[2] = mu[2]; c[3] = mu[3];
        c[4] = L10; c[5] = L20; c[6] = L21;
        c[7] = L30; c[8] = L31; c[9] = L32;
        c[10] = 1.0f / L00; c[11] = 1.0f / L11;
        c[12] = 1.0f / L22; c[13] = 1.0f / L33;
        c[14] = ck;
    }
    __syncthreads();
    const size_t row = (size_t)blockIdx.x * 256 + tid;
    float4 z = *(const float4*)(z_out + row * 4);
    float lp[10];
    float mx = -1e30f;
    #pragma unroll
    for (int k = 0; k < 10; ++k) {
        const float* q = cst + k * 16;
        float v0 = z.x - q[0], v1 = z.y - q[1], v2 = z.z - q[2], v3 = z.w - q[3];
        float y0 = v0 * q[10];
        float y1 = (v1 - q[4] * y0) * q[11];
        float y2 = (v2 - q[5] * y0 - q[6] * y1) * q[12];
        float y3 = (v3 - q[7] * y0 - q[8] * y1 - q[9] * y2) * q[13];
        float m = y0 * y0 + y1 * y1 + y2 * y2 + y3 * y3;
        lp[k] = q[14] - 0.5f * m;
        mx = fmaxf(mx, lp[k]);
    }
    float s = 0.0f;
    #pragma unroll
    for (int k = 0; k < 10; ++k) s += __expf(lp[k] - mx);
    e_out[row] = -(mx + __logf(s));
}

extern "C" void kernel_launch(void* const* d_in, const int* in_sizes, int n_in,
                              void* d_out, int out_size, void* d_ws, size_t ws_size,
                              hipStream_t stream) {
    const float* x = (const float*)d_in[0];
    const float* W[10];
    const float* B[10];
    for (int i = 0; i < 10; ++i) {
        W[i] = (const float*)d_in[1 + 2 * i];
        B[i] = (const float*)d_in[2 + 2 * i];
    }
    const int N = in_sizes[0] / 120;
    const int nblk = N / TPB;

    float* out   = (float*)d_out;
    float* e_out = out;                  // [N]
    float* g_out = out + (size_t)N;      // [N,10]
    float* z_out = out + (size_t)11 * N; // [N,4]
    float* c_out = out + (size_t)15 * N; // [10,4,4]

    float* ws   = (float*)d_ws;
    float* w8t  = ws;                    // 7200
    float* sums = ws + 7200;             // 152

    prep_k<<<29, 256, 0, stream>>>(W[7], w8t, sums);

    mlp_k<<<nblk, TPB, 0, stream>>>(
        x,
        W[0], B[0],
        W[1], B[1],
        W[2], B[2],
        W[3], B[3],
        W[4], B[4],
        W[5], B[5],
        W[6], B[6],
        w8t,  B[7],
        W[8], B[8],
        W[9], B[9],
        g_out, z_out,
        sums);

    energy_k<<<N / 256, 256, 0, stream>>>(z_out, sums, e_out, c_out, N);
}

// Round 7
// 287.030 us; speedup vs baseline: 2.4247x; 1.8507x over previous
//
#include <hip/hip_runtime.h>
#include <hip/hip_bf16.h>

// DAGMM forward, round 7 (= round-6 MFMA design, resubmitted after container
// failure; never measured).
//   K0 prep_k   : pack all 10 weights as zero-padded transposed f16 (Wt[Npad][Kpad])
//                 + padded f32 biases into d_ws; zero the 150-float sums slot.
//   K1 mlp_k    : 4 independent waves/block, 32 rows/wave (2 M-tiles of 16).
//                 Per layer: A-frags from per-wave XOR-swizzled LDS ping-pong
//                 buffers (L1's A straight from global x, f32->f16 in regs);
//                 B-frags from L2-resident packed weights; accumulate fp32 via
//                 v_mfma_f32_16x16x32_f16; bias+tanh on C-frags; softmax via
//                 shfl_xor butterflies. gamma/zc to d_out (zc in fp32 from acc).
//   K2 stats_k  : column-parallel GMM moments (block-deterministic reduce,
//                 atomicAdd across blocks into sums).
//   K3 energy_k : consts/Cholesky redundant per block; triangular solve +
//                 logsumexp -> energy; block 0 writes cov.
//
// d_out (floats): [energy N][gamma N*10][zc N*4][cov 160]
// d_ws  (floats): [sums 152][bias 400 @152][wt f16 25600 @552] (~53.4 KB)

#define TPB 256

typedef _Float16 half8 __attribute__((ext_vector_type(8)));
typedef float f32x4 __attribute__((ext_vector_type(4)));

__device__ __forceinline__ float fast_tanh(float v) {
    float e = __expf(2.0f * v);
    return 1.0f - __fdividef(2.0f, e + 1.0f);
}

__device__ __forceinline__ float wave_sum(float v) {
    #pragma unroll
    for (int off = 32; off > 0; off >>= 1) v += __shfl_xor(v, off, 64);
    return v;
}

// ---------------- K0: pack weights (padded, transposed, f16) ----------------
__global__ __launch_bounds__(256) void prep_k(
    const float* __restrict__ w1, const float* __restrict__ b1,
    const float* __restrict__ w2, const float* __restrict__ b2,
    const float* __restrict__ w3, const float* __restrict__ b3,
    const float* __restrict__ w4, const float* __restrict__ b4,
    const float* __restrict__ w5, const float* __restrict__ b5,
    const float* __restrict__ w6, const float* __restrict__ b6,
    const float* __restrict__ w7, const float* __restrict__ b7,
    const float* __restrict__ w8, const float* __restrict__ b8,
    const float* __restrict__ w9, const float* __restrict__ b9,
    const float* __restrict__ w10, const float* __restrict__ b10,
    float* __restrict__ ws) {
    const int idx = blockIdx.x * 256 + threadIdx.x;
    const int woff[11] = {0,8192,10240,10752,11264,11776,12800,14848,23040,25088,25600};
    const int boff[11] = {0,64,96,112,128,144,176,240,368,384,400};
    const int KPs[10] = {128,64,32,32,32,32,32,64,128,32};
    const int Ks[10]  = {120,60,30,10,4,10,30,60,120,10};
    const int Ns[10]  = {60,30,10,4,10,30,60,120,10,10};
    const float* Wp[10] = {w1,w2,w3,w4,w5,w6,w7,w8,w9,w10};
    const float* Bp[10] = {b1,b2,b3,b4,b5,b6,b7,b8,b9,b10};

    if (idx < 152) ws[idx] = 0.0f;                 // sums slot
    if (idx < 400) {                               // padded biases
        int l = 0;
        while (idx >= boff[l + 1]) ++l;
        int n = idx - boff[l];
        ws[152 + idx] = (n < Ns[l]) ? Bp[l][n] : 0.0f;
    }
    if (idx < 25600) {                             // padded transposed f16 weights
        int l = 0;
        while (idx >= woff[l + 1]) ++l;
        int local = idx - woff[l];
        int kp = KPs[l];
        int n = local / kp, k = local % kp;
        _Float16* wt = (_Float16*)(ws + 552);
        wt[idx] = (k < Ks[l] && n < Ns[l]) ? (_Float16)Wp[l][k * Ns[l] + n]
                                           : (_Float16)0.0f;
    }
}

// ---------------- MFMA layer helpers ----------------
// Fragment layout (gfx950 16x16x32): A: row=lane&15, k=(lane>>4)*8+i (contig 8)
//                                    B: col=lane&15, k=(lane>>4)*8+i
//                                    C: col=lane&15, row=(lane>>4)*4+reg
// LDS activation tiles [32 rows][W cols] f16, XOR-swizzled: byte ^= (row&7)<<4.

template<int KP, int PIN>
__device__ __forceinline__ void loadA(half8 (&a)[2][KP / 32],
                                      const _Float16* buf, int c, int q) {
    #pragma unroll
    for (int m = 0; m < 2; ++m)
        #pragma unroll
        for (int kk = 0; kk < KP / 32; ++kk) {
            int row = m * 16 + c;
            int inrow = (kk * 32 + q * 8) * 2;
            a[m][kk] = *(const half8*)((const char*)buf + row * PIN +
                                       (inrow ^ ((row & 7) << 4)));
        }
}

template<int KP, int NP, int NPZ, int POUT, bool ACT, bool ZST>
__device__ __forceinline__ void core(const half8 (&a)[2][KP / 32],
                                     _Float16* bufout,
                                     const _Float16* __restrict__ wt,
                                     const float* __restrict__ bias,
                                     int c, int q, float* zbase) {
    constexpr int KS = KP / 32, NT = NP / 16;
    f32x4 acc[2][NT];
    #pragma unroll
    for (int nt = 0; nt < NT; ++nt) {
        float bv = bias[nt * 16 + c];
        #pragma unroll
        for (int m = 0; m < 2; ++m) acc[m][nt] = (f32x4){bv, bv, bv, bv};
    }
    #pragma unroll
    for (int nt = 0; nt < NT; ++nt)
        #pragma unroll
        for (int kk = 0; kk < KS; ++kk) {
            half8 b = *(const half8*)(wt + (nt * 16 + c) * KP + kk * 32 + q * 8);
            #pragma unroll
            for (int m = 0; m < 2; ++m)
                acc[m][nt] = __builtin_amdgcn_mfma_f32_16x16x32_f16(
                    a[m][kk], b, acc[m][nt], 0, 0, 0);
        }
    #pragma unroll
    for (int m = 0; m < 2; ++m)
        #pragma unroll
        for (int nt = 0; nt < NT; ++nt)
            #pragma unroll
            for (int r = 0; r < 4; ++r) {
                float v = acc[m][nt][r];
                if (ACT) v = fast_tanh(v);
                int row = m * 16 + q * 4 + r, col = nt * 16 + c;
                if (ZST && nt == 0) {
                    if (c < 4) zbase[row * 4 + c] = v;   // zc in fp32, pre-f16
                }
                *(_Float16*)((char*)bufout + row * POUT +
                             ((col * 2) ^ ((row & 7) << 4))) = (_Float16)v;
            }
    if (NPZ > NP) {   // zero-fill pad cols so next layer's K-padding is inert
        #pragma unroll
        for (int m = 0; m < 2; ++m)
            #pragma unroll
            for (int r = 0; r < 4; ++r) {
                int row = m * 16 + q * 4 + r, col = NP + c;
                *(_Float16*)((char*)bufout + row * POUT +
                             ((col * 2) ^ ((row & 7) << 4))) = (_Float16)0.0f;
            }
    }
}

// ---------------- K1: MFMA MLP ----------------
__global__ __launch_bounds__(TPB, 3) void mlp_k(
    const float* __restrict__ x, const float* __restrict__ ws,
    float* __restrict__ g_out, float* __restrict__ z_out) {

    __shared__ _Float16 sA[4][32 * 64];    // 4 KB/wave, pitch 128 B
    __shared__ _Float16 sB[4][32 * 128];   // 8 KB/wave, pitch 256 B

    const int tid = threadIdx.x, lane = tid & 63, wid = tid >> 6;
    const int c = lane & 15, q = lane >> 4;
    const int row0w = blockIdx.x * 128 + wid * 32;
    _Float16* bufA = sA[wid];
    _Float16* bufB = sB[wid];
    const _Float16* wt = (const _Float16*)(ws + 552);
    const float* bias = ws + 152;

    // ---- L1: A straight from global x (f32 -> f16), K=120 pad 128, N=60 pad 64
    {
        half8 ax[2][4];
        #pragma unroll
        for (int m = 0; m < 2; ++m)
            #pragma unroll
            for (int kk = 0; kk < 4; ++kk) {
                int row = row0w + m * 16 + c;
                int k0 = kk * 32 + q * 8;
                half8 v;
                if (kk == 3 && q == 3) {               // k 120..127: zero pad
                    #pragma unroll
                    for (int i = 0; i < 8; ++i) v[i] = (_Float16)0.0f;
                } else {
                    const float* p = x + (size_t)row * 120 + k0;
                    float4 u0 = *(const float4*)p;
                    float4 u1 = *(const float4*)(p + 4);
                    v[0] = (_Float16)u0.x; v[1] = (_Float16)u0.y;
                    v[2] = (_Float16)u0.z; v[3] = (_Float16)u0.w;
                    v[4] = (_Float16)u1.x; v[5] = (_Float16)u1.y;
                    v[6] = (_Float16)u1.z; v[7] = (_Float16)u1.w;
                }
                ax[m][kk] = v;
            }
        core<128, 64, 64, 128, true, false>(ax, bufA, wt + 0, bias + 0, c, q, nullptr);
    }
    // ---- L2: 60->30
    { half8 a[2][2]; loadA<64, 128>(a, bufA, c, q);
      core<64, 32, 32, 256, true, false>(a, bufB, wt + 8192, bias + 64, c, q, nullptr); }
    // ---- L3: 30->10 (zero-fill to 32)
    { half8 a[2][1]; loadA<32, 256>(a, bufB, c, q);
      core<32, 16, 32, 128, true, false>(a, bufA, wt + 10240, bias + 96, c, q, nullptr); }
    // ---- L4: 10->4 = zc (linear; fp32 store from acc)
    { half8 a[2][1]; loadA<32, 128>(a, bufA, c, q);
      core<32, 16, 32, 256, false, true>(a, bufB, wt + 10752, bias + 112, c, q,
                                         z_out + (size_t)row0w * 4); }
    // ---- L5: 4->10
    { half8 a[2][1]; loadA<32, 256>(a, bufB, c, q);
      core<32, 16, 32, 128, true, false>(a, bufA, wt + 11264, bias + 128, c, q, nullptr); }
    // ---- L6: 10->30
    { half8 a[2][1]; loadA<32, 128>(a, bufA, c, q);
      core<32, 32, 32, 256, true, false>(a, bufB, wt + 11776, bias + 144, c, q, nullptr); }
    // ---- L7: 30->60
    { half8 a[2][1]; loadA<32, 256>(a, bufB, c, q);
      core<32, 64, 64, 128, true, false>(a, bufA, wt + 12800, bias + 176, c, q, nullptr); }
    // ---- L8: 60->120 (linear reconstruction)
    { half8 a[2][2]; loadA<64, 128>(a, bufA, c, q);
      core<64, 128, 128, 256, false, false>(a, bufB, wt + 14848, bias + 240, c, q, nullptr); }
    // ---- L9: 120->10
    { half8 a[2][4]; loadA<128, 256>(a, bufB, c, q);
      core<128, 16, 32, 128, true, false>(a, bufA, wt + 23040, bias + 368, c, q, nullptr); }
    // ---- L10: 10->10 + softmax (inline; NT=1)
    {
        half8 a[2][1]; loadA<32, 128>(a, bufA, c, q);
        float bv = bias[384 + c];
        f32x4 acc[2];
        #pragma unroll
        for (int m = 0; m < 2; ++m) acc[m] = (f32x4){bv, bv, bv, bv};
        half8 b = *(const half8*)(wt + 25088 + c * 32 + q * 8);
        #pragma unroll
        for (int m = 0; m < 2; ++m)
            acc[m] = __builtin_amdgcn_mfma_f32_16x16x32_f16(a[m][0], b, acc[m], 0, 0, 0);
        #pragma unroll
        for (int m = 0; m < 2; ++m)
            #pragma unroll
            for (int r = 0; r < 4; ++r) {
                float lg = (c < 10) ? acc[m][r] : -1e30f;
                float mx = lg;
                #pragma unroll
                for (int msk = 8; msk > 0; msk >>= 1) mx = fmaxf(mx, __shfl_xor(mx, msk));
                float e = (c < 10) ? __expf(lg - mx) : 0.0f;
                float sm = e;
                #pragma unroll
                for (int msk = 8; msk > 0; msk >>= 1) sm += __shfl_xor(sm, msk);
                float g = __fdividef(e, sm);
                if (c < 10)
                    g_out[(size_t)(row0w + m * 16 + q * 4 + r) * 10 + c] = g;
            }
    }
}

// ---------------- K2: GMM moments (block-reduce, atomic across blocks) -------
__global__ __launch_bounds__(256) void stats_k(
    const float* __restrict__ g_out, const float* __restrict__ z_out,
    float* __restrict__ sums, int N) {
    const int kp = blockIdx.x >> 6;        // 0..4
    const int ch = blockIdx.x & 63;        // 0..63
    const int k0 = kp * 2;
    const int tid = threadIdx.x;
    const int rows = N >> 6;
    const int iters = rows >> 8;
    const int base = ch * rows;

    float a0[15], a1[15];
    #pragma unroll
    for (int i = 0; i < 15; ++i) { a0[i] = 0.f; a1[i] = 0.f; }

    #pragma unroll 2
    for (int m = 0; m < iters; ++m) {
        int r = base + m * 256 + tid;
        float4 z = *(const float4*)(z_out + (size_t)r * 4);
        float2 g01 = *(const float2*)(g_out + (size_t)r * 10 + k0);
        {
            float gv = g01.x;
            float t0 = gv * z.x, t1 = gv * z.y, t2 = gv * z.z, t3 = gv * z.w;
            a0[0] += gv; a0[1] += t0; a0[2] += t1; a0[3] += t2; a0[4] += t3;
            a0[5]  = fmaf(t0, z.x, a0[5]);  a0[6]  = fmaf(t0, z.y, a0[6]);
            a0[7]  = fmaf(t0, z.z, a0[7]);  a0[8]  = fmaf(t0, z.w, a0[8]);
            a0[9]  = fmaf(t1, z.y, a0[9]);  a0[10] = fmaf(t1, z.z, a0[10]);
            a0[11] = fmaf(t1, z.w, a0[11]); a0[12] = fmaf(t2, z.z, a0[12]);
            a0[13] = fmaf(t2, z.w, a0[13]); a0[14] = fmaf(t3, z.w, a0[14]);
        }
        {
            float gv = g01.y;
            float t0 = gv * z.x, t1 = gv * z.y, t2 = gv * z.z, t3 = gv * z.w;
            a1[0] += gv; a1[1] += t0; a1[2] += t1; a1[3] += t2; a1[4] += t3;
            a1[5]  = fmaf(t0, z.x, a1[5]);  a1[6]  = fmaf(t0, z.y, a1[6]);
            a1[7]  = fmaf(t0, z.z, a1[7]);  a1[8]  = fmaf(t0, z.w, a1[8]);
            a1[9]  = fmaf(t1, z.y, a1[9]);  a1[10] = fmaf(t1, z.z, a1[10]);
            a1[11] = fmaf(t1, z.w, a1[11]); a1[12] = fmaf(t2, z.z, a1[12]);
            a1[13] = fmaf(t2, z.w, a1[13]); a1[14] = fmaf(t3, z.w, a1[14]);
        }
    }
    #pragma unroll
    for (int i = 0; i < 15; ++i) { a0[i] = wave_sum(a0[i]); a1[i] = wave_sum(a1[i]); }

    __shared__ float wp[4][30];
    const int wave = tid >> 6, ln = tid & 63;
    if (ln == 0) {
        #pragma unroll
        for (int i = 0; i < 15; ++i) { wp[wave][i] = a0[i]; wp[wave][15 + i] = a1[i]; }
    }
    __syncthreads();
    if (tid < 30) {
        float s = (wp[0][tid] + wp[1][tid]) + (wp[2][tid] + wp[3][tid]);
        int k = k0 + tid / 15, i = tid % 15;
        atomicAdd(sums + k * 15 + i, s);
    }
}

// ---------------- K3: consts (redundant per block) + sample energy ----------
__global__ __launch_bounds__(256) void energy_k(
    const float* __restrict__ z_out, const float* __restrict__ sums,
    float* __restrict__ e_out, float* __restrict__ cov_out, int N) {
    __shared__ float sm[150];
    __shared__ float cst[160];
    const int tid = threadIdx.x;
    if (tid < 150) sm[tid] = sums[tid];
    __syncthreads();
    if (tid < 10) {
        const int k = tid;
        const float sg = sm[k * 15 + 0];
        const float inv = 1.0f / sg;
        float mu[4];
        #pragma unroll
        for (int d = 0; d < 4; ++d) mu[d] = sm[k * 15 + 1 + d] * inv;
        const int pd[10] = {0,0,0,0,1,1,1,2,2,3};
        const int pe[10] = {0,1,2,3,1,2,3,2,3,3};
        float cov[4][4];
        #pragma unroll
        for (int p = 0; p < 10; ++p) {
            float cv = sm[k * 15 + 5 + p] * inv - mu[pd[p]] * mu[pe[p]];
            cov[pd[p]][pe[p]] = cv;
            cov[pe[p]][pd[p]] = cv;
        }
        if (blockIdx.x == 0) {
            #pragma unroll
            for (int d = 0; d < 4; ++d)
                #pragma unroll
                for (int e = 0; e < 4; ++e)
                    cov_out[k * 16 + d * 4 + e] = cov[d][e];
        }
        #pragma unroll
        for (int d = 0; d < 4; ++d) cov[d][d] += 1e-6f;
        float L00 = sqrtf(cov[0][0]);
        float L10 = cov[1][0] / L00, L20 = cov[2][0] / L00, L30 = cov[3][0] / L00;
        float L11 = sqrtf(cov[1][1] - L10 * L10);
        float L21 = (cov[2][1] - L20 * L10) / L11;
        float L31 = (cov[3][1] - L30 * L10) / L11;
        float L22 = sqrtf(cov[2][2] - L20 * L20 - L21 * L21);
        float L32 = (cov[3][2] - L30 * L20 - L31 * L21) / L22;
        float L33 = sqrtf(cov[3][3] - L30 * L30 - L31 * L31 - L32 * L32);
        float logdet = 2.0f * (logf(L00) + logf(L11) + logf(L22) + logf(L33));
        float phi = sg / (float)N;
        const float log2pi = 1.8378770664093453f;
        float ck = logf(phi) - 0.5f * (logdet + 4.0f * log2pi);
        float* cc = cst + k * 16;
        cc[0] = mu[0]; cc[1] = mu[1]; cc[2] = mu[2]; cc[3] = mu[3];
        cc[4] = L10; cc[5] = L20; cc[6] = L21;
        cc[7] = L30; cc[8] = L31; cc[9] = L32;
        cc[10] = 1.0f / L00; cc[11] = 1.0f / L11;
        cc[12] = 1.0f / L22; cc[13] = 1.0f / L33;
        cc[14] = ck;
    }
    __syncthreads();
    const size_t row = (size_t)blockIdx.x * 256 + tid;
    float4 z = *(const float4*)(z_out + row * 4);
    float lp[10];
    float mx = -1e30f;
    #pragma unroll
    for (int k = 0; k < 10; ++k) {
        const float* qq = cst + k * 16;
        float v0 = z.x - qq[0], v1 = z.y - qq[1], v2 = z.z - qq[2], v3 = z.w - qq[3];
        float y0 = v0 * qq[10];
        float y1 = (v1 - qq[4] * y0) * qq[11];
        float y2 = (v2 - qq[5] * y0 - qq[6] * y1) * qq[12];
        float y3 = (v3 - qq[7] * y0 - qq[8] * y1 - qq[9] * y2) * qq[13];
        float m = y0 * y0 + y1 * y1 + y2 * y2 + y3 * y3;
        lp[k] = qq[14] - 0.5f * m;
        mx = fmaxf(mx, lp[k]);
    }
    float s = 0.0f;
    #pragma unroll
    for (int k = 0; k < 10; ++k) s += __expf(lp[k] - mx);
    e_out[row] = -(mx + __logf(s));
}

extern "C" void kernel_launch(void* const* d_in, const int* in_sizes, int n_in,
                              void* d_out, int out_size, void* d_ws, size_t ws_size,
                              hipStream_t stream) {
    const float* x = (const float*)d_in[0];
    const float* W[10];
    const float* B[10];
    for (int i = 0; i < 10; ++i) {
        W[i] = (const float*)d_in[1 + 2 * i];
        B[i] = (const float*)d_in[2 + 2 * i];
    }
    const int N = in_sizes[0] / 120;

    float* out   = (float*)d_out;
    float* e_out = out;                  // [N]
    float* g_out = out + (size_t)N;      // [N,10]
    float* z_out = out + (size_t)11 * N; // [N,4]
    float* c_out = out + (size_t)15 * N; // [10,4,4]

    float* ws   = (float*)d_ws;          // [sums 152][bias 400][wt f16 25600]
    float* sums = ws;

    prep_k<<<100, 256, 0, stream>>>(
        W[0], B[0], W[1], B[1], W[2], B[2], W[3], B[3], W[4], B[4],
        W[5], B[5], W[6], B[6], W[7], B[7], W[8], B[8], W[9], B[9], ws);

    mlp_k<<<N / 128, TPB, 0, stream>>>(x, ws, g_out, z_out);

    stats_k<<<5 * 64, 256, 0, stream>>>(g_out, z_out, sums, N);

    energy_k<<<N / 256, 256, 0, stream>>>(z_out, sums, e_out, c_out, N);
}